// Round 9
// baseline (254.816 us; speedup 1.0000x reference)
//
#include <hip/hip_runtime.h>

#define T_LEN     32768
#define KTAG      5
#define HID       1024
#define START_TAG 3
#define STOP_TAG  4
#define NEGV      (-10000.0f)
#define CHUNK     64
#define NCHUNK    512      // T_LEN / CHUNK
#define NSEG      16
#define SEGLEN    32       // NCHUNK / NSEG

// ---------------------------------------------------------------------------
// K1: emissions[t][k] = dot(feats[t], W[k]) + b[k].  One wave per row t.
// ---------------------------------------------------------------------------
__global__ __launch_bounds__(256) void k_emis(const float* __restrict__ feats,
                                              const float* __restrict__ W,
                                              const float* __restrict__ b,
                                              float* __restrict__ emis) {
    int tid  = blockIdx.x * 256 + threadIdx.x;
    int row  = tid >> 6;
    int lane = tid & 63;
    if (row >= T_LEN) return;

    const float4* f4 = (const float4*)feats + row * 256;
    const float4* Wq = (const float4*)W;

    float a0 = 0.f, a1 = 0.f, a2 = 0.f, a3 = 0.f, a4 = 0.f;
#pragma unroll
    for (int j = 0; j < 4; ++j) {
        float4 f  = f4[j * 64 + lane];
        float4 w0 = Wq[0 * 256 + j * 64 + lane];
        float4 w1 = Wq[1 * 256 + j * 64 + lane];
        float4 w2 = Wq[2 * 256 + j * 64 + lane];
        float4 w3 = Wq[3 * 256 + j * 64 + lane];
        float4 w4 = Wq[4 * 256 + j * 64 + lane];
        a0 += f.x * w0.x + f.y * w0.y + f.z * w0.z + f.w * w0.w;
        a1 += f.x * w1.x + f.y * w1.y + f.z * w1.z + f.w * w1.w;
        a2 += f.x * w2.x + f.y * w2.y + f.z * w2.z + f.w * w2.w;
        a3 += f.x * w3.x + f.y * w3.y + f.z * w3.z + f.w * w3.w;
        a4 += f.x * w4.x + f.y * w4.y + f.z * w4.z + f.w * w4.w;
    }
#pragma unroll
    for (int s = 1; s < 64; s <<= 1) {
        a0 += __shfl_xor(a0, s, 64);
        a1 += __shfl_xor(a1, s, 64);
        a2 += __shfl_xor(a2, s, 64);
        a3 += __shfl_xor(a3, s, 64);
        a4 += __shfl_xor(a4, s, 64);
    }
    if (lane < KTAG) {
        float r = (lane == 0) ? a0 : (lane == 1) ? a1 : (lane == 2) ? a2
                                   : (lane == 3) ? a3 : a4;
        emis[row * KTAG + lane] = r + b[lane];
    }
}

// ---------------------------------------------------------------------------
// K2: per-chunk max-plus matrix product P_c = M_{last} (x) ... (x) M_{first}.
// One wave per chunk; lanes 0..24 hold A[n][p], lane = n*5+p.
// ---------------------------------------------------------------------------
__global__ __launch_bounds__(64) void k_chunkmat(const float* __restrict__ emis,
                                                 const float* __restrict__ trans,
                                                 float* __restrict__ P) {
    int c    = blockIdx.x;
    int lane = threadIdx.x;
    if (lane >= 25) return;
    int n = lane / 5, p = lane % 5;

    float tr0 = trans[n * 5 + 0], tr1 = trans[n * 5 + 1], tr2 = trans[n * 5 + 2];
    float tr3 = trans[n * 5 + 3], tr4 = trans[n * 5 + 4];

    int t0 = c * CHUNK;
    float A = trans[n * 5 + p] + emis[t0 * KTAG + n];   // A = M_{t0}
    for (int j = 1; j < CHUNK; ++j) {
        float e  = emis[(t0 + j) * KTAG + n];
        float q0 = __shfl(A, 0 * 5 + p, 64);
        float q1 = __shfl(A, 1 * 5 + p, 64);
        float q2 = __shfl(A, 2 * 5 + p, 64);
        float q3 = __shfl(A, 3 * 5 + p, 64);
        float q4 = __shfl(A, 4 * 5 + p, 64);
        float m  = tr0 + q0;
        m = fmaxf(m, tr1 + q1);
        m = fmaxf(m, tr2 + q2);
        m = fmaxf(m, tr3 + q3);
        m = fmaxf(m, tr4 + q4);
        A = m + e;                                       // A = M_t (x) A
    }
    P[c * 25 + lane] = A;
}

// ---------------------------------------------------------------------------
// K3: single-block hierarchical scan over the 512 chunk matrices.
//  B1: wave w composes its 32 chunk matrices -> supermatrix S_w   (lanes<25)
//  B2: wave 0 propagates the init vector through the 16 S_w, computes the
//      terminal score/best tag                                    (lanes<5)
//  B3: wave w propagates v through its 32 chunks, storing chunk-start
//      vectors v_c                                                (lanes<5)
// ---------------------------------------------------------------------------
__global__ __launch_bounds__(1024) void k_scan(const float* __restrict__ P,
                                               const float* __restrict__ trans,
                                               float* __restrict__ vc,
                                               float* __restrict__ score_out,
                                               unsigned int* __restrict__ best_out) {
    __shared__ float Pl[NCHUNK * 25];
    __shared__ float Sl[NSEG * 25];
    __shared__ float vsup[NSEG * 5];

    int tid = threadIdx.x;
    for (int i = tid; i < NCHUNK * 25; i += 1024) Pl[i] = P[i];
    __syncthreads();

    int w = tid >> 6, lane = tid & 63;

    // ---- B1
    if (lane < 25) {
        int n = lane / 5, p = lane % 5;
        float A = Pl[(w * SEGLEN) * 25 + lane];
        for (int j = 1; j < SEGLEN; ++j) {
            const float* Pn = &Pl[(w * SEGLEN + j) * 25 + n * 5];
            float q0 = __shfl(A, 0 * 5 + p, 64);
            float q1 = __shfl(A, 1 * 5 + p, 64);
            float q2 = __shfl(A, 2 * 5 + p, 64);
            float q3 = __shfl(A, 3 * 5 + p, 64);
            float q4 = __shfl(A, 4 * 5 + p, 64);
            float m  = Pn[0] + q0;
            m = fmaxf(m, Pn[1] + q1);
            m = fmaxf(m, Pn[2] + q2);
            m = fmaxf(m, Pn[3] + q3);
            m = fmaxf(m, Pn[4] + q4);
            A = m;
        }
        Sl[w * 25 + lane] = A;
    }
    __syncthreads();

    // ---- B2 (wave 0, lanes 0..4; lane index == tag n)
    if (tid < 5) {
        float v = (tid == START_TAG) ? 0.0f : NEGV;
        for (int s = 0; s < NSEG; ++s) {
            vsup[s * 5 + tid] = v;
            float q0 = __shfl(v, 0, 64);
            float q1 = __shfl(v, 1, 64);
            float q2 = __shfl(v, 2, 64);
            float q3 = __shfl(v, 3, 64);
            float q4 = __shfl(v, 4, 64);
            const float* S = &Sl[s * 25 + tid * 5];
            float m = S[0] + q0;
            m = fmaxf(m, S[1] + q1);
            m = fmaxf(m, S[2] + q2);
            m = fmaxf(m, S[3] + q3);
            m = fmaxf(m, S[4] + q4);
            v = m;
        }
        float term = v + trans[STOP_TAG * 5 + tid];
        float c0 = __shfl(term, 0, 64);
        float c1 = __shfl(term, 1, 64);
        float c2 = __shfl(term, 2, 64);
        float c3 = __shfl(term, 3, 64);
        float c4 = __shfl(term, 4, 64);
        float bv = c0; int bi = 0;
        if (c1 > bv) { bv = c1; bi = 1; }
        if (c2 > bv) { bv = c2; bi = 2; }
        if (c3 > bv) { bv = c3; bi = 3; }
        if (c4 > bv) { bv = c4; bi = 4; }
        if (tid == 0) { score_out[0] = bv; best_out[0] = (unsigned int)bi; }
    }
    __syncthreads();

    // ---- B3
    if (lane < 5) {
        float v = vsup[w * 5 + lane];
        for (int j = 0; j < SEGLEN; ++j) {
            int c = w * SEGLEN + j;
            vc[c * 5 + lane] = v;
            const float* Pn = &Pl[c * 25 + lane * 5];
            float q0 = __shfl(v, 0, 64);
            float q1 = __shfl(v, 1, 64);
            float q2 = __shfl(v, 2, 64);
            float q3 = __shfl(v, 3, 64);
            float q4 = __shfl(v, 4, 64);
            float m  = Pn[0] + q0;
            m = fmaxf(m, Pn[1] + q1);
            m = fmaxf(m, Pn[2] + q2);
            m = fmaxf(m, Pn[3] + q3);
            m = fmaxf(m, Pn[4] + q4);
            v = m;
        }
    }
}

// ---------------------------------------------------------------------------
// K4: per-chunk replay from exact chunk-start vector: emit packed
// backpointers bp16[t] (3 bits per tag) and the chunk's composed
// backtrack map F16[c] (maps path[chunk_end] -> path[chunk_start-1]).
// One wave per chunk; lanes 0..4 hold v[n], n = lane.
// ---------------------------------------------------------------------------
__global__ __launch_bounds__(64) void k_replay(const float* __restrict__ emis,
                                               const float* __restrict__ trans,
                                               const float* __restrict__ vc,
                                               unsigned short* __restrict__ bp16,
                                               unsigned short* __restrict__ F16) {
    int c    = blockIdx.x;
    int lane = threadIdx.x;
    if (lane >= 5) return;
    int n = lane;

    float tr0 = trans[n * 5 + 0], tr1 = trans[n * 5 + 1], tr2 = trans[n * 5 + 2];
    float tr3 = trans[n * 5 + 3], tr4 = trans[n * 5 + 4];

    float v = vc[c * 5 + n];
    int G = n;                     // identity map
    int t0 = c * CHUNK;
    for (int j = 0; j < CHUNK; ++j) {
        int t = t0 + j;
        float e  = emis[t * KTAG + n];
        float q0 = __shfl(v, 0, 64);
        float q1 = __shfl(v, 1, 64);
        float q2 = __shfl(v, 2, 64);
        float q3 = __shfl(v, 3, 64);
        float q4 = __shfl(v, 4, 64);
        float c0 = tr0 + q0, c1 = tr1 + q1, c2 = tr2 + q2, c3 = tr3 + q3, c4 = tr4 + q4;
        float bv = c0; int bp = 0;
        if (c1 > bv) { bv = c1; bp = 1; }
        if (c2 > bv) { bv = c2; bp = 2; }
        if (c3 > bv) { bv = c3; bp = 3; }
        if (c4 > bv) { bv = c4; bp = 4; }
        v = bv + e;
        G = __shfl(G, bp, 64);     // G_new[n] = G_old[bp_t[n]]
        int b0 = __shfl(bp, 0, 64);
        int b1 = __shfl(bp, 1, 64);
        int b2 = __shfl(bp, 2, 64);
        int b3 = __shfl(bp, 3, 64);
        int b4 = __shfl(bp, 4, 64);
        if (lane == 0)
            bp16[t] = (unsigned short)(b0 | (b1 << 3) | (b2 << 6) | (b3 << 9) | (b4 << 12));
    }
    int g0 = __shfl(G, 0, 64);
    int g1 = __shfl(G, 1, 64);
    int g2 = __shfl(G, 2, 64);
    int g3 = __shfl(G, 3, 64);
    int g4 = __shfl(G, 4, 64);
    if (lane == 0)
        F16[c] = (unsigned short)(g0 | (g1 << 3) | (g2 << 6) | (g3 << 9) | (g4 << 12));
}

// ---------------------------------------------------------------------------
// K5: hierarchical suffix application of the chunk maps: produce
// Ec[c] = path tag at chunk c's last timestep.  Single wave.
// ---------------------------------------------------------------------------
__global__ __launch_bounds__(64) void k_back(const unsigned short* __restrict__ F16,
                                             const unsigned int* __restrict__ best_in,
                                             unsigned int* __restrict__ Ec) {
    __shared__ unsigned int sm[NSEG];
    __shared__ unsigned int esup[NSEG];
    int lane = threadIdx.x;

    if (lane < NSEG) {             // compose this segment's 32 maps (packed ALU)
        unsigned int G = 0u | (1u << 3) | (2u << 6) | (3u << 9) | (4u << 12);
        int base = lane * SEGLEN;
        for (int j = SEGLEN - 1; j >= 0; --j) {
            unsigned int f  = F16[base + j];
            unsigned int Gn = 0;
#pragma unroll
            for (int x = 0; x < 5; ++x) {
                unsigned int gx = (G >> (3 * x)) & 7u;
                unsigned int ex = (f >> (3 * gx)) & 7u;
                Gn |= ex << (3 * x);
            }
            G = Gn;                // G_new[x] = F_c[G_old[x]]
        }
        sm[lane] = G;
    }
    __syncthreads();
    if (lane == 0) {
        unsigned int E = best_in[0];
        for (int s = NSEG - 1; s >= 0; --s) {
            esup[s] = E;
            E = (sm[s] >> (3 * E)) & 7u;
        }
    }
    __syncthreads();
    if (lane < NSEG) {
        unsigned int E = esup[lane];
        int base = lane * SEGLEN;
        for (int j = SEGLEN - 1; j >= 0; --j) {
            Ec[base + j] = E;
            unsigned int f = F16[base + j];
            E = (f >> (3 * E)) & 7u;
        }
    }
}

// ---------------------------------------------------------------------------
// K6: emit the path. One wave per chunk; the 64 packed backpointer words
// live one-per-lane, the 64-step chase runs in registers via shuffles.
// out layout: out[0] = score, out[1 + t] = (float)path[t].
// ---------------------------------------------------------------------------
__global__ __launch_bounds__(64) void k_path(const unsigned short* __restrict__ bp16,
                                             const unsigned int* __restrict__ Ec,
                                             float* __restrict__ out) {
    int c    = blockIdx.x;
    int lane = threadIdx.x;
    int pk   = (int)bp16[c * 64 + lane];
    unsigned int carry = Ec[c];
    unsigned int mypath = 0;
#pragma unroll
    for (int j = 63; j >= 0; --j) {
        int pkj = __shfl(pk, j, 64);
        if (lane == j) mypath = carry;           // path[c*64 + j] = carry
        carry = ((unsigned int)pkj >> (3 * carry)) & 7u;
    }
    out[1 + c * 64 + lane] = (float)mypath;
}

// ---------------------------------------------------------------------------
extern "C" void kernel_launch(void* const* d_in, const int* in_sizes, int n_in,
                              void* d_out, int out_size, void* d_ws, size_t ws_size,
                              hipStream_t stream) {
    const float* feats = (const float*)d_in[0];   // [1, 32768, 1024]
    const float* W     = (const float*)d_in[1];   // [5, 1024]
    const float* b     = (const float*)d_in[2];   // [5]
    const float* trans = (const float*)d_in[3];   // [5, 5]
    float* out = (float*)d_out;                   // [1 + 32768]

    char* ws = (char*)d_ws;
    float*          emis = (float*)(ws + 0);              // 32768*5*4   = 655360
    float*          P    = (float*)(ws + 655360);         // 512*25*4    =  51200
    float*          vc   = (float*)(ws + 706560);         // 512*5*4     =  10240
    unsigned short* bp16 = (unsigned short*)(ws + 716800);// 32768*2     =  65536
    unsigned short* F16  = (unsigned short*)(ws + 782336);// 512*2       =   1024
    unsigned int*   Ec   = (unsigned int*)(ws + 783360);  // 512*4       =   2048
    unsigned int*   best = (unsigned int*)(ws + 785408);  // 4

    hipLaunchKernelGGL(k_emis,     dim3(8192), dim3(256),  0, stream, feats, W, b, emis);
    hipLaunchKernelGGL(k_chunkmat, dim3(NCHUNK), dim3(64), 0, stream, emis, trans, P);
    hipLaunchKernelGGL(k_scan,     dim3(1), dim3(1024),    0, stream, P, trans, vc, out, best);
    hipLaunchKernelGGL(k_replay,   dim3(NCHUNK), dim3(64), 0, stream, emis, trans, vc, bp16, F16);
    hipLaunchKernelGGL(k_back,     dim3(1), dim3(64),      0, stream, F16, best, Ec);
    hipLaunchKernelGGL(k_path,     dim3(NCHUNK), dim3(64), 0, stream, bp16, Ec, out);
}